// Round 5
// baseline (397.551 us; speedup 1.0000x reference)
//
#include <hip/hip_runtime.h>

#define HW 512
#define IMGPIX (HW * HW)
#define NSEG 254
#define NIMG 48
#define NGRP 32    // column groups in fused pass (16 cols each: 8 + 8 mirrored)
#define SLICE 521  // per-slot float2 LDS stride (512 data + skew; coprime banks)

// ---------------- 8-point DFT in registers (DIF, natural-order outputs) ----
__device__ __forceinline__ void dft8(float xr[8], float xi[8]) {
    const float C = 0.70710678118654752440f;
    float b0r = xr[0] + xr[4], b0i = xi[0] + xi[4];
    float b1r = xr[1] + xr[5], b1i = xi[1] + xi[5];
    float b2r = xr[2] + xr[6], b2i = xi[2] + xi[6];
    float b3r = xr[3] + xr[7], b3i = xi[3] + xi[7];
    float d4r = xr[0] - xr[4], d4i = xi[0] - xi[4];
    float d5r = xr[1] - xr[5], d5i = xi[1] - xi[5];
    float d6r = xr[2] - xr[6], d6i = xi[2] - xi[6];
    float d7r = xr[3] - xr[7], d7i = xi[3] - xi[7];
    float b4r = d4r, b4i = d4i;
    float b5r = C * (d5r + d5i), b5i = C * (d5i - d5r);   // * W8^1
    float b6r = d6i, b6i = -d6r;                          // * -i
    float b7r = C * (d7i - d7r), b7i = -C * (d7r + d7i);  // * W8^3
    float c0r = b0r + b2r, c0i = b0i + b2i;
    float c1r = b1r + b3r, c1i = b1i + b3i;
    float e2r = b0r - b2r, e2i = b0i - b2i;
    float e3r = b1r - b3r, e3i = b1i - b3i;
    float c3r = e3i, c3i = -e3r;                          // * -i
    float c4r = b4r + b6r, c4i = b4i + b6i;
    float c5r = b5r + b7r, c5i = b5i + b7i;
    float e6r = b4r - b6r, e6i = b4i - b6i;
    float e7r = b5r - b7r, e7i = b5i - b7i;
    float c7r = e7i, c7i = -e7r;                          // * -i
    xr[0] = c0r + c1r; xi[0] = c0i + c1i;
    xr[4] = c0r - c1r; xi[4] = c0i - c1i;
    xr[2] = e2r + c3r; xi[2] = e2i + c3i;
    xr[6] = e2r - c3r; xi[6] = e2i - c3i;
    xr[1] = c4r + c5r; xi[1] = c4i + c5i;
    xr[5] = c4r - c5r; xi[5] = c4i - c5i;
    xr[3] = e6r + c7r; xi[3] = e6i + c7i;
    xr[7] = e6r - c7r; xi[7] = e6i - c7i;
}

__device__ __forceinline__ void tw_apply(float xr[8], float xi[8], float ang) {
    float s, c;
    sincosf(ang, &s, &c);
    float pr = c, pi = s;
#pragma unroll
    for (int k = 1; k < 8; ++k) {
        float tr = xr[k] * pr - xi[k] * pi;
        float ti = xr[k] * pi + xi[k] * pr;
        xr[k] = tr; xi[k] = ti;
        if (k < 7) { float nr = pr * c - pi * s; pi = pr * s + pi * c; pr = nr; }
    }
}

// Per-wave 512-pt FFT. In: slot j holds point n = j*64 + l (natural order).
// Out: lane (hi=l>>3, lo=l&7), slot j3 holds X[hi + 8*lo + 64*j3].
// ex: wave-private float2 region (>=512 elems). XOR swizzles keep every b64
// exchange at the 4-way floor. No block barriers; same-wave LDS order via
// s_waitcnt only.
__device__ __forceinline__ void wave_fft512(float xr[8], float xi[8],
                                            float2* ex, int l) {
    const float TWO_PI = 6.28318530717958647692f;
    dft8(xr, xi);
    tw_apply(xr, xi, -TWO_PI * (float)l * (1.0f / 512.0f));
#pragma unroll
    for (int k1 = 0; k1 < 8; ++k1)
        ex[k1 * 64 + (l ^ (k1 << 3))] = make_float2(xr[k1], xi[k1]);
    asm volatile("s_waitcnt lgkmcnt(0)" ::: "memory");
    int hi = l >> 3, lo = l & 7;
#pragma unroll
    for (int m1 = 0; m1 < 8; ++m1) {
        float2 v = ex[hi * 64 + ((m1 ^ hi) << 3) + lo];
        xr[m1] = v.x; xi[m1] = v.y;
    }
    dft8(xr, xi);
    tw_apply(xr, xi, -TWO_PI * (float)lo * (1.0f / 64.0f));
#pragma unroll
    for (int j2 = 0; j2 < 8; ++j2)
        ex[hi * 64 + ((j2 ^ hi) << 3) + (lo ^ hi)] = make_float2(xr[j2], xi[j2]);
    asm volatile("s_waitcnt lgkmcnt(0)" ::: "memory");
#pragma unroll
    for (int m2 = 0; m2 < 8; ++m2) {
        float2 v = ex[hi * 64 + ((lo ^ hi) << 3) + (m2 ^ hi)];
        xr[m2] = v.x; xi[m2] = v.y;
    }
    dft8(xr, xi);
}

// Pass 1: FFT along contiguous axis; one row-FFT per wave, 4 waves/block.
// re = input, im = target (real-pair packing). No __syncthreads at all.
__global__ __launch_bounds__(256) void fft_rows_kernel(
    const float* __restrict__ input, const float* __restrict__ target,
    float2* __restrict__ F, int img_offset) {
    __shared__ float2 ex[4 * SLICE];
    int tid = threadIdx.x, w = tid >> 6, l = tid & 63;
    int x = blockIdx.x * 4 + w;
    int li = blockIdx.y;
    const float* ib = input + (size_t)(img_offset + li) * IMGPIX + (size_t)x * HW;
    const float* tb = target + (size_t)(img_offset + li) * IMGPIX + (size_t)x * HW;
    float xr[8], xi[8];
#pragma unroll
    for (int j = 0; j < 8; ++j) {
        xr[j] = ib[j * 64 + l];
        xi[j] = tb[j * 64 + l];
    }
    wave_fft512(xr, xi, ex + w * SLICE, l);
    float2* ob = F + ((size_t)li * HW + x) * HW;
    int hi = l >> 3, lo = l & 7;
#pragma unroll
    for (int j3 = 0; j3 < 8; ++j3)
        ob[hi + (lo << 3) + (j3 << 6)] = make_float2(xr[j3], xi[j3]);
}

// Zero the pixel map (rebuilt every call — no state across calls).
__global__ void zero_map_kernel(int* __restrict__ map) {
    int i = blockIdx.x * 256 + threadIdx.x;
    if (i < IMGPIX) map[i] = 0;
}

// Scatter points into per-pixel map: value = mult*2^24 + mult*seg.
// Bresenham circles of distinct radii are disjoint; duplicates (octant
// boundaries) share the seg, mult in {1,2}.
__global__ void build_map_kernel(const int* __restrict__ rows,
                                 const int* __restrict__ cols,
                                 const int* __restrict__ segs,
                                 int* __restrict__ map, int P) {
    int p = blockIdx.x * 256 + threadIdx.x;
    if (p >= P) return;
    atomicAdd(&map[rows[p] * HW + cols[p]], (1 << 24) + segs[p]);
}

// Fused pass 2: column FFT + gather. Block g handles 16 columns: left
// L = {8g+1..8g+8} and mirrors R = {504-8g..511-8g} (slot 15-s mirrors s).
// One 512-pt FFT per wave (16 waves). After the FFT the block holds u and v
// for every gathered point whose column is local; contributions (split from
// the packed real-pair FFT via conjugate symmetry) accumulate in LDS bins,
// then dump to per-(img,group) partials. Column 0 is never needed (r,c>=3);
// duplicate col 256 (g=31, slot 8) is excluded from contribution duty.
// NOTE: min-waves arg must stay low — (1024,8) caps VGPR at 32 and forces
// the register FFT to spill to scratch (round-4 regression: 337us, VALUBusy 8%).
__global__ __launch_bounds__(1024, 2) void fft_cols_gather_kernel(
    const float2* __restrict__ F, const int* __restrict__ map,
    float4* __restrict__ part, int img_offset) {
    __shared__ float2 tile[16 * SLICE];
    __shared__ float bins[NSEG * 4];
    int tid = threadIdx.x, w = tid >> 6, l = tid & 63;
    int g = blockIdx.x;
    int img = img_offset + blockIdx.y;
    const float2* buf = F + (size_t)blockIdx.y * IMGPIX;

    for (int i = tid; i < NSEG * 4; i += 1024) bins[i] = 0.0f;
#pragma unroll
    for (int it = 0; it < 8; ++it) {
        int e = it * 1024 + tid;
        int y = e >> 4, s = e & 15;
        int c = (s < 8) ? (8 * g + 1 + s) : (504 - 8 * g + s - 8);
        tile[s * SLICE + y] = buf[(size_t)y * HW + c];
    }
    __syncthreads();

    float xr[8], xi[8];
#pragma unroll
    for (int j = 0; j < 8; ++j) {
        float2 v = tile[w * SLICE + j * 64 + l];
        xr[j] = v.x; xi[j] = v.y;
    }
    wave_fft512(xr, xi, tile + w * SLICE, l);  // wave-private slice scratch
    int hi = l >> 3, lo = l & 7;
#pragma unroll
    for (int j3 = 0; j3 < 8; ++j3)
        tile[w * SLICE + hi + (lo << 3) + (j3 << 6)] = make_float2(xr[j3], xi[j3]);
    __syncthreads();

#pragma unroll
    for (int it = 0; it < 8; ++it) {
        int e = it * 1024 + tid;
        int y = e >> 4, s = e & 15;
        int c = (s < 8) ? (8 * g + 1 + s) : (504 - 8 * g + s - 8);
        int mv = map[(y << 9) + c];
        bool duty = (s < 8) || (c > 256);
        if (mv != 0 && duty) {
            int mult = mv >> 24;
            int seg = (mv & 0xFFFFFF) >> (mult - 1);
            float2 u = tile[s * SLICE + y];
            float2 v = tile[(15 - s) * SLICE + ((HW - y) & (HW - 1))];
            float ar = u.x + v.x, ai = u.y - v.y;
            float br = u.y + v.y, bi = v.x - u.x;
            float m = (float)mult;
            atomicAdd(&bins[seg * 4 + 0], m * (ar * br + ai * bi));
            atomicAdd(&bins[seg * 4 + 1], m * (ai * br - ar * bi));
            atomicAdd(&bins[seg * 4 + 2], m * (ar * ar + ai * ai));
            atomicAdd(&bins[seg * 4 + 3], m * (br * br + bi * bi));
        }
    }
    __syncthreads();
    float* pp = (float*)(part + ((size_t)img * NGRP + g) * NSEG);
    for (int i = tid; i < NSEG * 4; i += 1024) pp[i] = bins[i];
}

// Reduce 32 partials per (img,seg), FRC, weighted sum, bias.
__global__ __launch_bounds__(256) void final_kernel(
    const float4* __restrict__ part, const float* __restrict__ weight,
    const float* __restrict__ bias, float* __restrict__ out) {
    int img = blockIdx.x;
    int t = threadIdx.x;
    float val = 0.0f;
    if (t < NSEG) {
        float cr = 0.f, ci = 0.f, e1 = 0.f, e2 = 0.f;
        for (int gq = 0; gq < NGRP; ++gq) {
            float4 v = part[((size_t)img * NGRP + gq) * NSEG + t];
            cr += v.x; ci += v.y; e1 += v.z; e2 += v.w;
        }
        val = weight[t + 1] * (sqrtf(cr * cr + ci * ci) * rsqrtf(e1 * e2));
    }
    __shared__ float red[256];
    red[t] = val;
    __syncthreads();
    if (t < 64) {
        float s = red[t] + red[t + 64] + red[t + 128] + red[t + 192];
#pragma unroll
        for (int off = 32; off >= 1; off >>= 1) s += __shfl_down(s, off, 64);
        if (t == 0) out[img] = s + weight[0] + bias[0];
    }
}

extern "C" void kernel_launch(void* const* d_in, const int* in_sizes, int n_in,
                              void* d_out, int out_size, void* d_ws, size_t ws_size,
                              hipStream_t stream) {
    const float* input  = (const float*)d_in[0];
    const float* target = (const float*)d_in[1];
    const int* rows     = (const int*)d_in[2];
    const int* cols     = (const int*)d_in[3];
    const int* segs     = (const int*)d_in[4];
    const float* weight = (const float*)d_in[5];
    const float* bias   = (const float*)d_in[6];
    float* out = (float*)d_out;
    int P = in_sizes[2];

    char* ws = (char*)d_ws;
    int* map = (int*)ws;                                     // 1 MB
    size_t mapBytes = (size_t)IMGPIX * sizeof(int);
    float4* part = (float4*)(ws + mapBytes);                 // 48*32*254*16 B
    size_t partBytes = (size_t)NIMG * NGRP * NSEG * sizeof(float4);
    size_t off = mapBytes + partBytes;
    off = (off + 255) & ~(size_t)255;
    size_t remain = (ws_size > off) ? (ws_size - off) : 0;
    size_t perImg = (size_t)IMGPIX * sizeof(float2);         // 2 MB per image
    const int chs[10] = {48, 24, 16, 12, 8, 6, 4, 3, 2, 1};
    int CH = 1;
    for (int i = 0; i < 10; ++i)
        if ((size_t)chs[i] * perImg <= remain) { CH = chs[i]; break; }
    float2* F = (float2*)(ws + off);

    zero_map_kernel<<<IMGPIX / 256, 256, 0, stream>>>(map);
    build_map_kernel<<<(P + 255) / 256, 256, 0, stream>>>(rows, cols, segs, map, P);

    for (int k = 0; k < NIMG; k += CH) {
        dim3 g1(HW / 4, CH);
        fft_rows_kernel<<<g1, 256, 0, stream>>>(input, target, F, k);
        dim3 g2(NGRP, CH);
        fft_cols_gather_kernel<<<g2, 1024, 0, stream>>>(F, map, part, k);
    }
    final_kernel<<<NIMG, 256, 0, stream>>>(part, weight, bias, out);
}

// Round 6
// 216.804 us; speedup vs baseline: 1.8337x; 1.8337x over previous
//
#include <hip/hip_runtime.h>

#define HW 512
#define IMGPIX (HW * HW)
#define NSEG 254
#define NIMG 48
#define NGRP 32    // column groups: 16 cols each (8 left + 8 mirrored)
#define SLICE 521  // per-slot float2 LDS stride (512 data + skew; coprime banks)

// ---------------- 8-point DFT in registers (DIF, natural-order outputs) ----
__device__ __forceinline__ void dft8(float xr[8], float xi[8]) {
    const float C = 0.70710678118654752440f;
    float b0r = xr[0] + xr[4], b0i = xi[0] + xi[4];
    float b1r = xr[1] + xr[5], b1i = xi[1] + xi[5];
    float b2r = xr[2] + xr[6], b2i = xi[2] + xi[6];
    float b3r = xr[3] + xr[7], b3i = xi[3] + xi[7];
    float d4r = xr[0] - xr[4], d4i = xi[0] - xi[4];
    float d5r = xr[1] - xr[5], d5i = xi[1] - xi[5];
    float d6r = xr[2] - xr[6], d6i = xi[2] - xi[6];
    float d7r = xr[3] - xr[7], d7i = xi[3] - xi[7];
    float b4r = d4r, b4i = d4i;
    float b5r = C * (d5r + d5i), b5i = C * (d5i - d5r);   // * W8^1
    float b6r = d6i, b6i = -d6r;                          // * -i
    float b7r = C * (d7i - d7r), b7i = -C * (d7r + d7i);  // * W8^3
    float c0r = b0r + b2r, c0i = b0i + b2i;
    float c1r = b1r + b3r, c1i = b1i + b3i;
    float e2r = b0r - b2r, e2i = b0i - b2i;
    float e3r = b1r - b3r, e3i = b1i - b3i;
    float c3r = e3i, c3i = -e3r;                          // * -i
    float c4r = b4r + b6r, c4i = b4i + b6i;
    float c5r = b5r + b7r, c5i = b5i + b7i;
    float e6r = b4r - b6r, e6i = b4i - b6i;
    float e7r = b5r - b7r, e7i = b5i - b7i;
    float c7r = e7i, c7i = -e7r;                          // * -i
    xr[0] = c0r + c1r; xi[0] = c0i + c1i;
    xr[4] = c0r - c1r; xi[4] = c0i - c1i;
    xr[2] = e2r + c3r; xi[2] = e2i + c3i;
    xr[6] = e2r - c3r; xi[6] = e2i - c3i;
    xr[1] = c4r + c5r; xi[1] = c4i + c5i;
    xr[5] = c4r - c5r; xi[5] = c4i - c5i;
    xr[3] = e6r + c7r; xi[3] = e6i + c7i;
    xr[7] = e6r - c7r; xi[7] = e6i - c7i;
}

__device__ __forceinline__ void tw_apply(float xr[8], float xi[8], float ang) {
    float s, c;
    sincosf(ang, &s, &c);
    float pr = c, pi = s;
#pragma unroll
    for (int k = 1; k < 8; ++k) {
        float tr = xr[k] * pr - xi[k] * pi;
        float ti = xr[k] * pi + xi[k] * pr;
        xr[k] = tr; xi[k] = ti;
        if (k < 7) { float nr = pr * c - pi * s; pi = pr * s + pi * c; pr = nr; }
    }
}

// Per-wave 512-pt FFT. In: slot j holds point n = j*64 + l (natural order).
// Out: lane (hi=l>>3, lo=l&7), slot j3 holds X[hi + 8*lo + 64*j3].
// ex: wave-private float2 region (>=512 elems). XOR swizzles keep every b64
// exchange at the 4-way floor. No block barriers; same-wave LDS order via
// s_waitcnt only.
__device__ __forceinline__ void wave_fft512(float xr[8], float xi[8],
                                            float2* ex, int l) {
    const float TWO_PI = 6.28318530717958647692f;
    dft8(xr, xi);
    tw_apply(xr, xi, -TWO_PI * (float)l * (1.0f / 512.0f));
#pragma unroll
    for (int k1 = 0; k1 < 8; ++k1)
        ex[k1 * 64 + (l ^ (k1 << 3))] = make_float2(xr[k1], xi[k1]);
    asm volatile("s_waitcnt lgkmcnt(0)" ::: "memory");
    int hi = l >> 3, lo = l & 7;
#pragma unroll
    for (int m1 = 0; m1 < 8; ++m1) {
        float2 v = ex[hi * 64 + ((m1 ^ hi) << 3) + lo];
        xr[m1] = v.x; xi[m1] = v.y;
    }
    dft8(xr, xi);
    tw_apply(xr, xi, -TWO_PI * (float)lo * (1.0f / 64.0f));
#pragma unroll
    for (int j2 = 0; j2 < 8; ++j2)
        ex[hi * 64 + ((j2 ^ hi) << 3) + (lo ^ hi)] = make_float2(xr[j2], xi[j2]);
    asm volatile("s_waitcnt lgkmcnt(0)" ::: "memory");
#pragma unroll
    for (int m2 = 0; m2 < 8; ++m2) {
        float2 v = ex[hi * 64 + ((lo ^ hi) << 3) + (m2 ^ hi)];
        xr[m2] = v.x; xi[m2] = v.y;
    }
    dft8(xr, xi);
}

// Pass 1: FFT along contiguous axis; one row-FFT per wave, 4 waves/block.
// re = input, im = target (real-pair packing). No __syncthreads at all.
__global__ __launch_bounds__(256) void fft_rows_kernel(
    const float* __restrict__ input, const float* __restrict__ target,
    float2* __restrict__ F, int img_offset) {
    __shared__ float2 ex[4 * SLICE];
    int tid = threadIdx.x, w = tid >> 6, l = tid & 63;
    int x = blockIdx.x * 4 + w;
    int li = blockIdx.y;
    const float* ib = input + (size_t)(img_offset + li) * IMGPIX + (size_t)x * HW;
    const float* tb = target + (size_t)(img_offset + li) * IMGPIX + (size_t)x * HW;
    float xr[8], xi[8];
#pragma unroll
    for (int j = 0; j < 8; ++j) {
        xr[j] = ib[j * 64 + l];
        xi[j] = tb[j * 64 + l];
    }
    wave_fft512(xr, xi, ex + w * SLICE, l);
    float2* ob = F + ((size_t)li * HW + x) * HW;
    int hi = l >> 3, lo = l & 7;
#pragma unroll
    for (int j3 = 0; j3 < 8; ++j3)
        ob[hi + (lo << 3) + (j3 << 6)] = make_float2(xr[j3], xi[j3]);
}

// Zero the pixel map (rebuilt every call — no state across calls).
__global__ void zero_map_kernel(int* __restrict__ map) {
    int i = blockIdx.x * 256 + threadIdx.x;
    if (i < IMGPIX) map[i] = 0;
}

// Scatter points into per-pixel map: value = mult*2^24 + mult*seg.
// Bresenham circles of distinct radii are disjoint; duplicates (octant
// boundaries) share the seg, mult in {1,2}.
__global__ void build_map_kernel(const int* __restrict__ rows,
                                 const int* __restrict__ cols,
                                 const int* __restrict__ segs,
                                 int* __restrict__ map, int P) {
    int p = blockIdx.x * 256 + threadIdx.x;
    if (p >= P) return;
    atomicAdd(&map[rows[p] * HW + cols[p]], (1 << 24) + segs[p]);
}

// Fused pass 2: column FFT + gather. 512 threads / 8 waves (NOT 1024: hipcc
// caps 1024-thread kernels at ~36 VGPR and the register FFT churns — rounds
// 4/5 regression). Block g owns 16 columns: left {8g+1..8g+8} (slot s<8),
// mirrors {504-8g..511-8g} (slot s>=8; mirror of slot s is 15-s). Wave w
// runs TWO sequential 512-pt FFTs (slots w, w+8), registers reused.
// Gather exploits central symmetry: pair (p, pbar) contributes z+conj(z)
// => cross is real; process canonical half only (left cols, c<256; col 256
// canonical iff y<256), weight m per pair, 3 accumulators (cr, e1, e2).
// The uniform pair x2 and packing x2 scales cancel in |cross|/sqrt(e1*e2).
__global__ __launch_bounds__(512) void fft_cols_gather_kernel(
    const float2* __restrict__ F, const int* __restrict__ map,
    float* __restrict__ part, int img_offset) {
    __shared__ float2 tile[16 * SLICE];
    __shared__ float bins[NSEG * 3];
    int tid = threadIdx.x, w = tid >> 6, l = tid & 63;
    int g = blockIdx.x;
    int img = img_offset + blockIdx.y;
    const float2* buf = F + (size_t)blockIdx.y * IMGPIX;

    for (int i = tid; i < NSEG * 3; i += 512) bins[i] = 0.0f;
#pragma unroll
    for (int it = 0; it < 16; ++it) {
        int e = it * 512 + tid;
        int y = e >> 4, s = e & 15;
        int c = (s < 8) ? (8 * g + 1 + s) : (504 - 8 * g + s - 8);
        tile[s * SLICE + y] = buf[(size_t)y * HW + c];
    }
    __syncthreads();

#pragma unroll 1
    for (int q = 0; q < 2; ++q) {
        int slot = w + q * 8;
        float xr[8], xi[8];
#pragma unroll
        for (int j = 0; j < 8; ++j) {
            float2 v = tile[slot * SLICE + j * 64 + l];
            xr[j] = v.x; xi[j] = v.y;
        }
        wave_fft512(xr, xi, tile + slot * SLICE, l);  // slot-private scratch
        int hi = l >> 3, lo = l & 7;
#pragma unroll
        for (int j3 = 0; j3 < 8; ++j3)
            tile[slot * SLICE + hi + (lo << 3) + (j3 << 6)] =
                make_float2(xr[j3], xi[j3]);
    }
    __syncthreads();

    // Canonical gather over left slots only: 8 cols x 512 y = 4096 pixels.
#pragma unroll
    for (int it = 0; it < 8; ++it) {
        int e = it * 512 + tid;
        int y = e >> 3, s = e & 7;
        int c = 8 * g + 1 + s;
        bool duty = (c < 256) || (c == 256 && y < 256);
        int mv = duty ? map[(y << 9) + c] : 0;
        if (mv != 0) {
            int mult = mv >> 24;
            int seg = (mv & 0xFFFFFF) >> (mult - 1);
            float2 u = tile[s * SLICE + y];
            float2 v = tile[(15 - s) * SLICE + ((HW - y) & (HW - 1))];
            float ar = u.x + v.x, ai = u.y - v.y;
            float br = u.y + v.y, bi = v.x - u.x;
            float m = (float)mult;
            atomicAdd(&bins[seg * 3 + 0], m * (ar * br + ai * bi));
            atomicAdd(&bins[seg * 3 + 1], m * (ar * ar + ai * ai));
            atomicAdd(&bins[seg * 3 + 2], m * (br * br + bi * bi));
        }
    }
    __syncthreads();
    float* pp = part + ((size_t)img * NGRP + g) * (NSEG * 3);
    for (int i = tid; i < NSEG * 3; i += 512) pp[i] = bins[i];
}

// Reduce 32 partials per (img,seg), FRC, weighted sum, bias.
__global__ __launch_bounds__(256) void final_kernel(
    const float* __restrict__ part, const float* __restrict__ weight,
    const float* __restrict__ bias, float* __restrict__ out) {
    int img = blockIdx.x;
    int t = threadIdx.x;
    float val = 0.0f;
    if (t < NSEG) {
        float cr = 0.f, e1 = 0.f, e2 = 0.f;
        for (int gq = 0; gq < NGRP; ++gq) {
            const float* pp = part + ((size_t)img * NGRP + gq) * (NSEG * 3) + t * 3;
            cr += pp[0]; e1 += pp[1]; e2 += pp[2];
        }
        val = weight[t + 1] * (fabsf(cr) * rsqrtf(e1 * e2));
    }
    __shared__ float red[256];
    red[t] = val;
    __syncthreads();
    if (t < 64) {
        float s = red[t] + red[t + 64] + red[t + 128] + red[t + 192];
#pragma unroll
        for (int off = 32; off >= 1; off >>= 1) s += __shfl_down(s, off, 64);
        if (t == 0) out[img] = s + weight[0] + bias[0];
    }
}

extern "C" void kernel_launch(void* const* d_in, const int* in_sizes, int n_in,
                              void* d_out, int out_size, void* d_ws, size_t ws_size,
                              hipStream_t stream) {
    const float* input  = (const float*)d_in[0];
    const float* target = (const float*)d_in[1];
    const int* rows     = (const int*)d_in[2];
    const int* cols     = (const int*)d_in[3];
    const int* segs     = (const int*)d_in[4];
    const float* weight = (const float*)d_in[5];
    const float* bias   = (const float*)d_in[6];
    float* out = (float*)d_out;
    int P = in_sizes[2];

    char* ws = (char*)d_ws;
    int* map = (int*)ws;                                     // 1 MB
    size_t mapBytes = (size_t)IMGPIX * sizeof(int);
    float* part = (float*)(ws + mapBytes);                   // 48*32*254*3*4 B
    size_t partBytes = (size_t)NIMG * NGRP * NSEG * 3 * sizeof(float);
    size_t off = mapBytes + partBytes;
    off = (off + 255) & ~(size_t)255;
    size_t remain = (ws_size > off) ? (ws_size - off) : 0;
    size_t perImg = (size_t)IMGPIX * sizeof(float2);         // 2 MB per image
    const int chs[10] = {48, 24, 16, 12, 8, 6, 4, 3, 2, 1};
    int CH = 1;
    for (int i = 0; i < 10; ++i)
        if ((size_t)chs[i] * perImg <= remain) { CH = chs[i]; break; }
    float2* F = (float2*)(ws + off);

    zero_map_kernel<<<IMGPIX / 256, 256, 0, stream>>>(map);
    build_map_kernel<<<(P + 255) / 256, 256, 0, stream>>>(rows, cols, segs, map, P);

    for (int k = 0; k < NIMG; k += CH) {
        dim3 g1(HW / 4, CH);
        fft_rows_kernel<<<g1, 256, 0, stream>>>(input, target, F, k);
        dim3 g2(NGRP, CH);
        fft_cols_gather_kernel<<<g2, 512, 0, stream>>>(F, map, part, k);
    }
    final_kernel<<<NIMG, 256, 0, stream>>>(part, weight, bias, out);
}